// Round 6
// baseline (220.050 us; speedup 1.0000x reference)
//
#include <hip/hip_runtime.h>

typedef unsigned short u16;
typedef __bf16 bf16x8 __attribute__((ext_vector_type(8)));
typedef float   f32x4 __attribute__((ext_vector_type(4)));
typedef unsigned short u16x8 __attribute__((ext_vector_type(8)));

// ---------- helpers ----------
__device__ __forceinline__ u16 f2bf(float f) {
    unsigned int u = __builtin_bit_cast(unsigned int, f);
    u = u + 0x7FFFu + ((u >> 16) & 1u);   // round-to-nearest-even
    return (u16)(u >> 16);
}
__device__ __forceinline__ void gload16(const void* g, void* l) {
    __builtin_amdgcn_global_load_lds(
        (__attribute__((address_space(1))) void*)g,
        (__attribute__((address_space(3))) void*)l,
        16, 0, 0);
}

// ---------- kernel: Wq [K][N] fp32 -> WqT [N][K] bf16 ----------
__global__ __launch_bounds__(256) void transpose_cvt(const float* __restrict__ W,
                                                     u16* __restrict__ Wt) {
    __shared__ u16 tile[64][65];
    const int c0 = blockIdx.x * 64;
    const int r0 = blockIdx.y * 64;
    const int col = threadIdx.x & 63;
    const int rb  = (threadIdx.x >> 6) * 16;
    #pragma unroll
    for (int rr = 0; rr < 16; ++rr)
        tile[rb + rr][col] = f2bf(W[(size_t)(r0 + rb + rr) * 1024 + c0 + col]);
    __syncthreads();
    const int k = threadIdx.x & 63;
    #pragma unroll
    for (int rr = 0; rr < 16; ++rr) {
        int n = c0 + rb + rr;
        Wt[(size_t)n * 1024 + r0 + k] = tile[k][rb + rr];
    }
}

// ---------- kernel: W2T[b][j][h*64+d] = sum_e M0[b,h,d,e]*Wo[h*64+e][j] ----------
// Also zeroes ssq (no separate memset dispatch).
__global__ __launch_bounds__(256) void build_w2t(const float* __restrict__ M0,
                                                 const float* __restrict__ Wo,
                                                 u16* __restrict__ W2T,
                                                 float* __restrict__ ssq) {
    const int jq = blockIdx.x, h = blockIdx.y, b = blockIdx.z;
    const int tid = threadIdx.x;
    const int lin = (b * 16 + h) * 4 + jq;       // 0..255
    if (lin < 128) ssq[lin * 256 + tid] = 0.f;   // 128*256 = 32768 rows
    const int j = jq * 256 + tid;
    __shared__ float m0s[64 * 64];
    const float* m0p = M0 + ((size_t)b * 16 + h) * 4096;
    for (int i = tid; i < 4096; i += 256) m0s[i] = m0p[i];
    __syncthreads();
    float wo[64];
    #pragma unroll
    for (int e = 0; e < 64; ++e) wo[e] = Wo[(size_t)(h * 64 + e) * 1024 + j];
    u16* outp = W2T + (size_t)b * 1024 * 1024 + (size_t)j * 1024 + h * 64;
    #pragma unroll 1
    for (int d = 0; d < 64; ++d) {
        float s = 0.f;
        #pragma unroll
        for (int e = 0; e < 64; ++e) s += m0s[d * 64 + e] * wo[e];
        outp[d] = f2bf(s);
    }
}

// ======================= GEMM1: P = h(fp32) @ WqT^T ========================
// A is fp32, staged DIRECTLY via global_load_lds into LDS as fp32 (160 KiB:
// A fp32 dbuf 4x32KB + B bf16 single-buf 2x16KB); converted to bf16 at
// fragment-read (v_cvt, RNE — same rounding as f2bf). Kills the separate
// cvt_bf16 kernel (32 us) and the 128 MB hbf round-trip.
// B single-buffer is safe: WqT = 2 MB, L2-resident; staged P3, read next P1
// (2-phase window >> L2 latency). A keeps full dbuf: staged P4 into the buf
// just finished reading, consumed 2 iters later (5-phase window, HBM-safe).
// vmcnt(8)@P4 keeps the 8 A-gloads in flight across the barrier (T4).
// Swizzle (derived, 16B-granular): store source col = (sl*4)^(((c*4+l4)&7)<<2),
// read byte ^= ((rm&7)<<4); identity: elems(R,b) = (b^((R&7)<<4))>>2.
// [R2 lesson: no reg-staged loads in the vmcnt queue. R4: no cross-GEMM
//  fusion. R5: barrier count is not the cost; LDS-epi epilogue reverted
//  to R1 scalar u16 stores (77.4us-verified, write BW not binding).]
__global__ __launch_bounds__(512, 2) void gemm1_f32a(
    const float* __restrict__ A, const u16* __restrict__ Bt,
    u16* __restrict__ C, float* __restrict__ ssq) {
    __shared__ __align__(16) u16 lds[81920];   // 163840 B == CU max
    const int K = 1024, N = 1024;
    const int tid  = threadIdx.x;
    const int lane = tid & 63;
    const int w    = tid >> 6;       // 0..7
    const int wm   = w >> 2;         // 0..1
    const int wn   = w & 3;          // 0..3

    // XCD swizzle: 512 blocks = 128 mt x 4 nt; each XCD owns 16 consecutive mt.
    const int id  = blockIdx.x;
    const int xcd = id & 7;
    const int loc = id >> 3;
    const int mt  = xcd * 16 + (loc >> 2);
    const int nt  = loc & 3;
    const int m0  = mt * 256;
    const int n0  = nt * 256;

    char* const ldsb = (char*)lds;

    // ---- B staging (bf16, single buffer at byte 131072) ----
    const int l3 = lane >> 3;
    const int co = ((lane & 7) ^ l3) * 8;
    const u16* gB = Bt + (size_t)(n0 + w * 16 + l3) * K + co;
    auto stB = [&](int h, int kt) {
        const u16* s = gB + (size_t)(h * 128) * K + kt * 64;
        char* d = ldsb + 131072 + h * 16384 + w * 2048;
        gload16(s, d);
        gload16(s + (size_t)8 * K, d + 1024);
    };

    // ---- A staging (fp32, dbuf slots (buf*2+h)*32768) ----
    const int l4 = lane >> 4;        // 0..3
    const int sl = lane & 15;
    auto stA = [&](int buf, int h, int kt) {
        #pragma unroll
        for (int c = 0; c < 4; ++c) {
            const int r   = w * 16 + c * 4 + l4;
            const int coA = (sl * 4) ^ (((c * 4 + l4) & 7) << 2);
            const float* s = A + (size_t)(m0 + h * 128 + r) * K + kt * 64 + coA;
            char* d = ldsb + (buf * 2 + h) * 32768 + w * 4096 + c * 1024;
            gload16(s, d);
        }
    };

    // ---- fragment reads ----
    const int rm   = lane & 15;
    const int kgA  = l4 * 32;                // A logical k-byte (fp32 row=256B)
    const int kqB  = l4 * 16;                // B logical k-byte (bf16 row=128B)
    const int swz  = (rm & 7) << 4;
    auto ldAf = [&](int buf, int qm, int m, int k_) -> bf16x8 {
        const int r = qm * 64 + m * 16 + rm;
        const char* p = ldsb + (buf * 2 + wm) * 32768 + r * 256;
        const int off = (k_ * 128 + kgA) ^ swz;
        f32x4 v0 = *(const f32x4*)(p + off);
        f32x4 v1 = *(const f32x4*)(p + (off ^ 16));
        bf16x8 f;
        #pragma unroll
        for (int e = 0; e < 4; ++e) { f[e] = (__bf16)v0[e]; f[4 + e] = (__bf16)v1[e]; }
        return f;
    };
    auto ldB = [&](int qn, int n, int ks) -> bf16x8 {
        const int rb = (wn & 1) * 64 + qn * 32 + n * 16 + rm;
        return *(const bf16x8*)(ldsb + 131072 + (wn >> 1) * 16384
                                + rb * 128 + ((ks * 64 + kqB) ^ swz));
    };

    f32x4 acc[8][4] = {};
    bf16x8 a[8];
    bf16x8 b[2][4];

#define LOADAF(buf, qm)                                                        \
    { _Pragma("unroll") for (int m_ = 0; m_ < 4; ++m_) {                       \
        _Pragma("unroll") for (int k_ = 0; k_ < 2; ++k_)                       \
            a[m_ * 2 + k_] = ldAf(buf, qm, m_, k_); } }
#define LOADB1(qn)                                                             \
    { _Pragma("unroll") for (int n_ = 0; n_ < 2; ++n_) {                       \
        _Pragma("unroll") for (int k_ = 0; k_ < 2; ++k_)                       \
            b[qn][n_ * 2 + k_] = ldB(qn, n_, k_); } }
#define MFMAQ(qm, qn)                                                          \
    { __builtin_amdgcn_s_setprio(1);                                           \
      _Pragma("unroll") for (int m_ = 0; m_ < 4; ++m_) {                       \
        _Pragma("unroll") for (int n_ = 0; n_ < 2; ++n_) {                     \
          _Pragma("unroll") for (int k_ = 0; k_ < 2; ++k_)                     \
            acc[(qm) * 4 + m_][(qn) * 2 + n_] =                                \
                __builtin_amdgcn_mfma_f32_16x16x32_bf16(                       \
                    a[m_ * 2 + k_], b[qn][n_ * 2 + k_],                        \
                    acc[(qm) * 4 + m_][(qn) * 2 + n_], 0, 0, 0); } }           \
      __builtin_amdgcn_s_setprio(0); }
#define LGKM0 asm volatile("s_waitcnt lgkmcnt(0)" ::: "memory")
#define BAR __builtin_amdgcn_s_barrier()

    const int nit = K >> 6;          // 16 K-tiles, 1 per iter

    // ---- prologue: A(0)->buf0, B(0), A(1)->buf1; confirm tile0, keep A(1) ----
    stA(0, 0, 0); stA(0, 1, 0);
    stB(0, 0);    stB(1, 0);
    stA(1, 0, 1); stA(1, 1, 1);
    asm volatile("s_waitcnt vmcnt(8)" ::: "memory");
    BAR;

    #pragma unroll 1
    for (int i = 0; i < nit; ++i) {
        const int a_  = i & 1;
        const int Tn  = (i + 1) & 15;
        const int Tp2 = (i + 2) & 15;

        // P1
        LOADAF(a_, 0); LOADB1(0);
        BAR; LGKM0;
        MFMAQ(0, 0);
        BAR;
        // P2
        LOADB1(1);
        BAR; LGKM0;
        MFMAQ(0, 1);
        BAR;
        // P3  (B(i) reads all completed by P2's end barrier -> restage B)
        LOADAF(a_, 1);
        stB(0, Tn); stB(1, Tn);
        BAR; LGKM0;
        MFMAQ(1, 0);
        BAR;
        // P4  (A(i) reads done by P3's barrier -> restage buf a_ with A(i+2))
        stA(a_, 0, Tp2); stA(a_, 1, Tp2);
        asm volatile("s_waitcnt vmcnt(8)" ::: "memory");  // confirm A(i+1)+B(i+1)
        BAR;
        MFMAQ(1, 1);
        BAR;
    }
#undef LOADAF
#undef LOADB1
#undef MFMAQ
#undef LGKM0
#undef BAR

    // ---- epilogue: scalar u16 stores (R1-verified fastest) + ssq ----
    asm volatile("s_waitcnt vmcnt(0)" ::: "memory");   // drain wrap-stages
    __syncthreads();
    const int cn = lane & 15;
    const int rq = (lane >> 4) * 4;
    float* lred = (float*)lds;
    if (tid < 256) lred[tid] = 0.f;
    __syncthreads();
    #pragma unroll
    for (int m = 0; m < 8; ++m) {
        const int rbase = wm * 128 + m * 16 + rq;
        #pragma unroll
        for (int r = 0; r < 4; ++r) {
            const size_t rowoff = (size_t)(m0 + rbase + r) * N;
            float s = 0.f;
            #pragma unroll
            for (int n = 0; n < 4; ++n) {
                float x = acc[m][n][r];
                s += x * x;
                C[rowoff + n0 + wn * 64 + n * 16 + cn] = f2bf(x);
            }
            s += __shfl_xor(s, 1);
            s += __shfl_xor(s, 2);
            s += __shfl_xor(s, 4);
            s += __shfl_xor(s, 8);
            if (cn == 0) atomicAdd(&lred[rbase + r], s);
        }
    }
    __syncthreads();
    if (tid < 256) atomicAdd(&ssq[m0 + tid], lred[tid]);
}

// ======================= GEMM2: out = s[m]*(P @ W2T^T) =====================
// R5 epoch-shifted template, bf16 operands, 128 KiB dbuf LDS (measured
// <=80.7 us). Single instantiation (no template) to avoid co-compilation
// codegen perturbation (rule #19).
__global__ __launch_bounds__(512, 2) void gemm2_k(
    const u16* __restrict__ A, const u16* __restrict__ Bt,
    float* __restrict__ C, const float* __restrict__ ssq) {
    __shared__ __align__(16) u16 lds[65536];   // 131072 B
    const int K = 1024, N = 1024;
    const int tid  = threadIdx.x;
    const int lane = tid & 63;
    const int w    = tid >> 6;
    const int wm   = w >> 2;
    const int wn   = w & 3;

    const int id  = blockIdx.x;
    const int xcd = id & 7;
    const int loc = id >> 3;
    const int mt  = xcd * 16 + (loc >> 2);
    const int nt  = loc & 3;
    const int m0  = mt * 256;
    const int n0  = nt * 256;
    const u16* Btb = Bt + (size_t)(m0 >> 13) * (size_t)(1024 * 1024);

    char* const ldsb = (char*)lds;

    const int l3 = lane >> 3;
    const int co = ((lane & 7) ^ l3) * 8;
    const u16* gA = A   + (size_t)(m0 + w * 16 + l3) * K + co;
    const u16* gB = Btb + (size_t)(n0 + w * 16 + l3) * K + co;
    const int wdst = w * 2048;
    auto stA = [&](int buf, int h, int kt) {
        const u16* s = gA + (size_t)(h * 128) * K + kt * 64;
        char* d = ldsb + (buf * 2 + h) * 16384 + wdst;
        gload16(s, d);
        gload16(s + (size_t)8 * K, d + 1024);
    };
    auto stB = [&](int buf, int h, int kt) {
        const u16* s = gB + (size_t)(h * 128) * K + kt * 64;
        char* d = ldsb + 65536 + (buf * 2 + h) * 16384 + wdst;
        gload16(s, d);
        gload16(s + (size_t)8 * K, d + 1024);
    };

    const int rm   = lane & 15;
    const int kq   = (lane >> 4) * 16;
    const int swzr = (rm & 7) << 4;
    auto ldA = [&](int buf, int qm, int m, int ks) -> bf16x8 {
        const int row = qm * 64 + m * 16 + rm;
        return *(const bf16x8*)(ldsb + (buf * 2 + wm) * 16384 + row * 128
                                + ((ks * 64 + kq) ^ swzr));
    };
    auto ldB = [&](int buf, int qn, int n, int ks) -> bf16x8 {
        const int row = (wn & 1) * 64 + qn * 32 + n * 16 + rm;
        return *(const bf16x8*)(ldsb + 65536 + (buf * 2 + (wn >> 1)) * 16384
                                + row * 128 + ((ks * 64 + kq) ^ swzr));
    };

    f32x4 acc[8][4] = {};
    bf16x8 a[8];
    bf16x8 b[2][4];

#define LOADA(buf, qm)                                                         \
    { _Pragma("unroll") for (int m_ = 0; m_ < 4; ++m_) {                       \
        _Pragma("unroll") for (int k_ = 0; k_ < 2; ++k_)                       \
            a[m_ * 2 + k_] = ldA(buf, qm, m_, k_); } }
#define LOADB(buf, qn)                                                         \
    { _Pragma("unroll") for (int n_ = 0; n_ < 2; ++n_) {                       \
        _Pragma("unroll") for (int k_ = 0; k_ < 2; ++k_)                       \
            b[qn][n_ * 2 + k_] = ldB(buf, qn, n_, k_); } }
#define MFMAQ(qm, qn)                                                          \
    { __builtin_amdgcn_s_setprio(1);                                           \
      _Pragma("unroll") for (int m_ = 0; m_ < 4; ++m_) {                       \
        _Pragma("unroll") for (int n_ = 0; n_ < 2; ++n_) {                     \
          _Pragma("unroll") for (int k_ = 0; k_ < 2; ++k_)                     \
            acc[(qm) * 4 + m_][(qn) * 2 + n_] =                                \
                __builtin_amdgcn_mfma_f32_16x16x32_bf16(                       \
                    a[m_ * 2 + k_], b[qn][n_ * 2 + k_],                        \
                    acc[(qm) * 4 + m_][(qn) * 2 + n_], 0, 0, 0); } }           \
      __builtin_amdgcn_s_setprio(0); }
#define LGKM0 asm volatile("s_waitcnt lgkmcnt(0)" ::: "memory")
#define VMC2 asm volatile("s_waitcnt vmcnt(2)" ::: "memory")
#define BAR __builtin_amdgcn_s_barrier()

    const int nkt = K >> 6;          // 16
    const int nit = nkt >> 1;        // 8

    stA(0, 0, 0); stA(0, 1, 0); stB(0, 0, 0); stB(0, 1, 0);
    stA(1, 0, 1); stA(1, 1, 1);
    asm volatile("s_waitcnt vmcnt(4)" ::: "memory");
    BAR;
    LOADA(0, 0); LOADB(0, 0);
    LGKM0;

    #pragma unroll 1
    for (int i = 0; i < nit; ++i) {
        const int T1 = 2 * i + 1;
        int T2 = 2 * i + 2; if (T2 >= nkt) T2 -= nkt;   // wrap: waste-stage
        int T3 = 2 * i + 3; if (T3 >= nkt) T3 -= nkt;

        // E1
        MFMAQ(0, 0);
        LOADB(0, 1);  LGKM0;
        stB(1, 0, T1);
        BAR;
        // E2
        MFMAQ(0, 1);
        LOADA(0, 1);  LGKM0;
        stB(1, 1, T1);
        BAR;
        // E3
        MFMAQ(1, 0);
        stA(0, 0, T2);
        VMC2;
        BAR;
        // E4
        MFMAQ(1, 1);
        LOADA(1, 0); LOADB(1, 0);  LGKM0;
        stA(0, 1, T2);
        BAR;
        // E5
        MFMAQ(0, 0);
        LOADB(1, 1);  LGKM0;
        stB(0, 0, T2);
        BAR;
        // E6
        MFMAQ(0, 1);
        LOADA(1, 1);  LGKM0;
        stB(0, 1, T2);
        BAR;
        // E7
        MFMAQ(1, 0);
        stA(1, 0, T3);
        VMC2;
        BAR;
        // E8
        MFMAQ(1, 1);
        LOADA(0, 0); LOADB(0, 0);  LGKM0;
        stA(1, 1, T3);
        BAR;
    }
#undef LOADA
#undef LOADB
#undef MFMAQ
#undef LGKM0
#undef VMC2
#undef BAR

    // ---- epilogue: row scale + scalar fp32 stores ----
    asm volatile("s_waitcnt vmcnt(0)" ::: "memory");
    __syncthreads();
    const int cn = lane & 15;
    const int rq = (lane >> 4) * 4;
    float* lred = (float*)lds;
    if (tid < 256) {
        float q = ssq[m0 + tid];
        lred[tid] = 1.0f / fmaxf(sqrtf(q), 1e-12f);
    }
    __syncthreads();
    #pragma unroll
    for (int m = 0; m < 8; ++m) {
        const int rbase = wm * 128 + m * 16 + rq;
        #pragma unroll
        for (int r = 0; r < 4; ++r) {
            const size_t rowoff = (size_t)(m0 + rbase + r) * N;
            const float sc = lred[rbase + r];
            #pragma unroll
            for (int n = 0; n < 4; ++n)
                C[rowoff + n0 + wn * 64 + n * 16 + cn] = acc[m][n][r] * sc;
        }
    }
}

// ---------- launch ----------
// B=4, S=8192, HID=PROJ=1024, NH=16, HD=64; M = B*S = 32768
// cvt_bf16 + hbf deleted: gemm1 consumes fp32 h directly via fp32-LDS staging.
extern "C" void kernel_launch(void* const* d_in, const int* in_sizes, int n_in,
                              void* d_out, int out_size, void* d_ws, size_t ws_size,
                              hipStream_t stream) {
    const float* h  = (const float*)d_in[0];   // [4,8192,1024]
    const float* Wq = (const float*)d_in[1];   // [1024,1024]
    const float* Wo = (const float*)d_in[7];   // [1024,1024]
    const float* M0 = (const float*)d_in[8];   // [4,16,64,64]
    float* out = (float*)d_out;

    char* ws = (char*)d_ws;
    u16*   P    = (u16*)(ws);                  // 67,108,864 B
    u16*   WqT  = (u16*)(ws + 67108864);       //  2,097,152 B
    u16*   W2T  = (u16*)(ws + 69206016);       //  8,388,608 B
    float* ssq  = (float*)(ws + 77594624);     //    131,072 B  (end: 77,725,696)

    transpose_cvt<<<dim3(16, 16), 256, 0, stream>>>(Wq, WqT);
    build_w2t<<<dim3(4, 16, 4), 256, 0, stream>>>(M0, Wo, W2T, ssq);  // + ssq=0
    // P = h @ Wq (bf16 out, un-normalized) + per-row ssq via atomics
    gemm1_f32a<<<512, 512, 0, stream>>>(h, WqT, P, ssq);
    // out = (1/max(sqrt(ssq),1e-12))[m] * (P @ W2T[batch]) ; batch = m >> 13
    gemm2_k<<<512, 512, 0, stream>>>(P, W2T, out, ssq);
}

// Round 7
// 208.651 us; speedup vs baseline: 1.0546x; 1.0546x over previous
//
#include <hip/hip_runtime.h>

typedef unsigned short u16;
typedef __bf16 bf16x8 __attribute__((ext_vector_type(8)));
typedef float   f32x4 __attribute__((ext_vector_type(4)));
typedef unsigned short u16x8 __attribute__((ext_vector_type(8)));

// ---------- helpers ----------
__device__ __forceinline__ u16 f2bf(float f) {
    unsigned int u = __builtin_bit_cast(unsigned int, f);
    u = u + 0x7FFFu + ((u >> 16) & 1u);   // round-to-nearest-even
    return (u16)(u >> 16);
}
__device__ __forceinline__ void gload16(const void* g, void* l) {
    __builtin_amdgcn_global_load_lds(
        (__attribute__((address_space(1))) void*)g,
        (__attribute__((address_space(3))) void*)l,
        16, 0, 0);
}

// ---------- merged prep: cvt_bf16 | WqT transpose | W2T build + ssq zero ----
// One dispatch, grid-partitioned (saves 3 launch boundaries + memset dispatch
// vs R1). Each section is the R1-verified kernel body with a blockIdx remap.
//  blocks [0,16384):      hbf = bf16(h)                (grid 16384 x 256)
//  blocks [16384,16640):  WqT[n][k] = bf16(Wq[k][n])   (256 blocks)
//  blocks [16640,16896):  W2T build + ssq zeroing      (256 blocks)
__global__ __launch_bounds__(256) void prep(
    const float* __restrict__ h,  u16* __restrict__ hbf,
    const float* __restrict__ Wq, u16* __restrict__ WqT,
    const float* __restrict__ M0, const float* __restrict__ Wo,
    u16* __restrict__ W2T, float* __restrict__ ssq) {
    __shared__ __align__(16) char smem[16384];
    const int bid = blockIdx.x;
    const int tid = threadIdx.x;

    if (bid < 16384) {
        // ---- cvt_bf16: 4,194,304 x 8 elems, fully covered ----
        const int i = bid * 256 + tid;
        const f32x4* xp = (const f32x4*)h + (size_t)i * 2;
        f32x4 a = xp[0], b = xp[1];
        u16x8 o;
        o[0]=f2bf(a[0]); o[1]=f2bf(a[1]); o[2]=f2bf(a[2]); o[3]=f2bf(a[3]);
        o[4]=f2bf(b[0]); o[5]=f2bf(b[1]); o[6]=f2bf(b[2]); o[7]=f2bf(b[3]);
        ((u16x8*)hbf)[i] = o;
    } else if (bid < 16640) {
        // ---- transpose_cvt: Wq [K][N] fp32 -> WqT [N][K] bf16 ----
        u16 (*tile)[65] = (u16(*)[65])smem;     // 64x65 u16 = 8320 B
        const int local = bid - 16384;
        const int c0 = (local & 15) * 64;
        const int r0 = (local >> 4) * 64;
        const int col = tid & 63;
        const int rb  = (tid >> 6) * 16;
        #pragma unroll
        for (int rr = 0; rr < 16; ++rr)
            tile[rb + rr][col] = f2bf(Wq[(size_t)(r0 + rb + rr) * 1024 + c0 + col]);
        __syncthreads();
        const int k = tid & 63;
        #pragma unroll
        for (int rr = 0; rr < 16; ++rr) {
            int n = c0 + rb + rr;
            WqT[(size_t)n * 1024 + r0 + k] = tile[k][rb + rr];
        }
    } else {
        // ---- build_w2t + ssq zero ----
        const int local = bid - 16640;           // 0..255
        const int jq = local & 3;
        const int hh = (local >> 2) & 15;
        const int bb = local >> 6;
        if (local < 128) ssq[local * 256 + tid] = 0.f;   // 128*256 = 32768 rows
        const int j = jq * 256 + tid;
        float* m0s = (float*)smem;               // 4096 floats = 16384 B
        const float* m0p = M0 + ((size_t)bb * 16 + hh) * 4096;
        for (int i = tid; i < 4096; i += 256) m0s[i] = m0p[i];
        __syncthreads();
        float wo[64];
        #pragma unroll
        for (int e = 0; e < 64; ++e) wo[e] = Wo[(size_t)(hh * 64 + e) * 1024 + j];
        u16* outp = W2T + (size_t)bb * 1024 * 1024 + (size_t)j * 1024 + hh * 64;
        #pragma unroll 1
        for (int d = 0; d < 64; ++d) {
            float s = 0.f;
            #pragma unroll
            for (int e = 0; e < 64; ++e) s += m0s[d * 64 + e] * wo[e];
            outp[d] = f2bf(s);
        }
    }
}

// ---------- GEMM: C[M,N] = A[M,K] * Bt[N,K]^T, bf16 in, fp32 acc ----------
// R1-VERIFIED template (77.4 us per dispatch, bank-conflict 0, MfmaUtil 37%).
// 256x256 tile, BK=64, 8 waves (2Mx4N), 128 KiB dbuf LDS, 8-phase schedule
// (T3+T4 counted vmcnt), st-swizzle (T2), setprio (T5). Scalar epilogues.
// [Session ledger: R2/R6 fp32-A staging, R3 LDS epilogue, R4 fusion, R5
//  epoch-shift all measured neutral-or-worse than this exact structure.]
template <int ACC_SSQ, int HAS_SCALE, typename CT>
__global__ __launch_bounds__(512, 2) void gemm256(const u16* __restrict__ A,
                                                  const u16* __restrict__ Bt,
                                                  CT* __restrict__ C,
                                                  float* __restrict__ ssq,
                                                  int M, int N, int K,
                                                  int bt_batch_stride, int rpb_log2) {
    __shared__ __align__(16) u16 lds[65536];   // 131072 B
    const int tid  = threadIdx.x;
    const int lane = tid & 63;
    const int w    = tid >> 6;       // 0..7
    const int wm   = w >> 2;         // 0..1
    const int wn   = w & 3;          // 0..3

    // XCD swizzle: 512 blocks = 128 mt x 4 nt; each XCD owns 16 consecutive mt.
    const int id  = blockIdx.x;
    const int xcd = id & 7;
    const int loc = id >> 3;
    const int mt  = xcd * 16 + (loc >> 2);
    const int nt  = loc & 3;
    const int m0  = mt * 256;
    const int n0  = nt * 256;
    const u16* Btb = Bt + (size_t)(m0 >> rpb_log2) * (size_t)bt_batch_stride;

    char* const ldsb = (char*)lds;

    // ---- staging: gload_lds, per-lane global src carries inverse swizzle ----
    const int l3 = lane >> 3;
    const int co = ((lane & 7) ^ l3) * 8;
    const u16* gA = A   + (size_t)(m0 + w * 16 + l3) * K + co;
    const u16* gB = Btb + (size_t)(n0 + w * 16 + l3) * K + co;
    const int wdst = w * 2048;
    auto stA = [&](int buf, int h, int kt) {
        const u16* s = gA + (size_t)(h * 128) * K + kt * 64;
        char* d = ldsb + (buf * 2 + h) * 16384 + wdst;
        gload16(s, d);
        gload16(s + (size_t)8 * K, d + 1024);
    };
    auto stB = [&](int buf, int h, int kt) {
        const u16* s = gB + (size_t)(h * 128) * K + kt * 64;
        char* d = ldsb + 65536 + (buf * 2 + h) * 16384 + wdst;
        gload16(s, d);
        gload16(s + (size_t)8 * K, d + 1024);
    };

    // ---- fragment reads (swizzled ds_read_b128) ----
    const int rm   = lane & 15;
    const int kq   = (lane >> 4) * 16;
    const int swzr = (rm & 7) << 4;
    auto ldA = [&](int buf, int qm, int m, int ks) -> bf16x8 {
        const int row = qm * 64 + m * 16 + rm;
        return *(const bf16x8*)(ldsb + (buf * 2 + wm) * 16384 + row * 128
                                + ((ks * 64 + kq) ^ swzr));
    };
    auto ldB = [&](int buf, int qn, int n, int ks) -> bf16x8 {
        const int row = (wn & 1) * 64 + qn * 32 + n * 16 + rm;
        return *(const bf16x8*)(ldsb + 65536 + (buf * 2 + (wn >> 1)) * 16384
                                + row * 128 + ((ks * 64 + kq) ^ swzr));
    };

    f32x4 acc[8][4] = {};
    bf16x8 a[8];
    bf16x8 b[2][4];

#define LOADA(buf, qm)                                                         \
    { _Pragma("unroll") for (int m_ = 0; m_ < 4; ++m_) {                       \
        _Pragma("unroll") for (int k_ = 0; k_ < 2; ++k_)                       \
            a[m_ * 2 + k_] = ldA(buf, qm, m_, k_); } }
#define LOADB(buf, qn)                                                         \
    { _Pragma("unroll") for (int n_ = 0; n_ < 2; ++n_) {                       \
        _Pragma("unroll") for (int k_ = 0; k_ < 2; ++k_)                       \
            b[qn][n_ * 2 + k_] = ldB(buf, qn, n_, k_); } }
#define MFMAQ(qm, qn)                                                          \
    { __builtin_amdgcn_s_setprio(1);                                           \
      _Pragma("unroll") for (int m_ = 0; m_ < 4; ++m_) {                       \
        _Pragma("unroll") for (int n_ = 0; n_ < 2; ++n_) {                     \
          _Pragma("unroll") for (int k_ = 0; k_ < 2; ++k_)                     \
            acc[(qm) * 4 + m_][(qn) * 2 + n_] =                                \
                __builtin_amdgcn_mfma_f32_16x16x32_bf16(                       \
                    a[m_ * 2 + k_], b[qn][n_ * 2 + k_],                        \
                    acc[(qm) * 4 + m_][(qn) * 2 + n_], 0, 0, 0); } }           \
      __builtin_amdgcn_s_setprio(0); }

    const int nkt = K >> 6;          // 16
    const int nit = nkt >> 1;        // 8

    // ---- prologue: tile0 (all 4 halves) + tile1 (B halves) ----
    stA(0, 0, 0); stA(0, 1, 0); stB(0, 0, 0); stB(0, 1, 0);
    stB(1, 0, 1); stB(1, 1, 1);
    asm volatile("s_waitcnt vmcnt(4)" ::: "memory");
    __builtin_amdgcn_s_barrier();

    #pragma unroll 1
    for (int i = 0; i < nit; ++i) {
        const int T1 = 2 * i + 1;
        int T2 = 2 * i + 2; if (T2 >= nkt) T2 -= nkt;   // wrap: waste-stage
        int T3 = 2 * i + 3; if (T3 >= nkt) T3 -= nkt;

        // P1
        LOADA(0, 0); LOADB(0, 0);
        stA(1, 0, T1);
        asm volatile("s_waitcnt lgkmcnt(8)" ::: "memory");
        __builtin_amdgcn_s_barrier();
        asm volatile("s_waitcnt lgkmcnt(0)" ::: "memory");
        MFMAQ(0, 0);
        __builtin_amdgcn_s_barrier();
        // P2
        LOADB(0, 1);
        stA(1, 1, T1);
        __builtin_amdgcn_s_barrier();
        asm volatile("s_waitcnt lgkmcnt(0)" ::: "memory");
        MFMAQ(0, 1);
        __builtin_amdgcn_s_barrier();
        // P3
        LOADA(0, 1);
        stB(0, 0, T2);
        __builtin_amdgcn_s_barrier();
        asm volatile("s_waitcnt lgkmcnt(0)" ::: "memory");
        MFMAQ(1, 0);
        __builtin_amdgcn_s_barrier();
        // P4
        stB(0, 1, T2);
        asm volatile("s_waitcnt vmcnt(4)" ::: "memory");
        __builtin_amdgcn_s_barrier();
        MFMAQ(1, 1);
        __builtin_amdgcn_s_barrier();
        // P5
        LOADA(1, 0); LOADB(1, 0);
        stA(0, 0, T2);
        asm volatile("s_waitcnt lgkmcnt(8)" ::: "memory");
        __builtin_amdgcn_s_barrier();
        asm volatile("s_waitcnt lgkmcnt(0)" ::: "memory");
        MFMAQ(0, 0);
        __builtin_amdgcn_s_barrier();
        // P6
        LOADB(1, 1);
        stA(0, 1, T2);
        __builtin_amdgcn_s_barrier();
        asm volatile("s_waitcnt lgkmcnt(0)" ::: "memory");
        MFMAQ(0, 1);
        __builtin_amdgcn_s_barrier();
        // P7
        LOADA(1, 1);
        stB(1, 0, T3);
        __builtin_amdgcn_s_barrier();
        asm volatile("s_waitcnt lgkmcnt(0)" ::: "memory");
        MFMAQ(1, 0);
        __builtin_amdgcn_s_barrier();
        // P8
        stB(1, 1, T3);
        asm volatile("s_waitcnt vmcnt(4)" ::: "memory");
        __builtin_amdgcn_s_barrier();
        MFMAQ(1, 1);
        __builtin_amdgcn_s_barrier();
    }
#undef LOADA
#undef LOADB
#undef MFMAQ

    // ---- epilogue ----  C layout: col=lane&15, row=(lane>>4)*4+reg [m89]
    asm volatile("s_waitcnt vmcnt(0)" ::: "memory");   // drain wrap-stages
    __syncthreads();
    float* lred = (float*)lds;   // 256 floats (row scales or row ssq)
    if constexpr (HAS_SCALE) {
        if (tid < 256) {
            float q = ssq[m0 + tid];
            lred[tid] = 1.0f / fmaxf(sqrtf(q), 1e-12f);
        }
        __syncthreads();
    }
    if constexpr (ACC_SSQ) {
        if (tid < 256) lred[tid] = 0.f;
        __syncthreads();
    }
    const int cn = lane & 15;
    const int rq = (lane >> 4) * 4;
    #pragma unroll
    for (int m = 0; m < 8; ++m) {
        const int rbase = wm * 128 + m * 16 + rq;
        #pragma unroll
        for (int r = 0; r < 4; ++r) {
            const size_t rowoff = (size_t)(m0 + rbase + r) * N;
            float s = 0.f;
            #pragma unroll
            for (int n = 0; n < 4; ++n) {
                float x = acc[m][n][r];
                if constexpr (HAS_SCALE) x *= lred[rbase + r];
                if constexpr (ACC_SSQ) s += x * x;
                const int col = n0 + wn * 64 + n * 16 + cn;
                if constexpr (sizeof(CT) == 2) ((u16*)C)[rowoff + col] = f2bf(x);
                else                           C[rowoff + col] = x;
            }
            if constexpr (ACC_SSQ) {
                s += __shfl_xor(s, 1);
                s += __shfl_xor(s, 2);
                s += __shfl_xor(s, 4);
                s += __shfl_xor(s, 8);
                if (cn == 0) atomicAdd(&lred[rbase + r], s);  // wn-waves share row
            }
        }
    }
    if constexpr (ACC_SSQ) {
        __syncthreads();
        if (tid < 256) atomicAdd(&ssq[m0 + tid], lred[tid]);  // 4 n-blocks per row
    }
}

// ---------- launch ----------
// B=4, S=8192, HID=PROJ=1024, NH=16, HD=64; M = B*S = 32768
// hbf lives in d_out's first half (dead after gemm1; gemm2 overwrites all
// of d_out — stream-ordered, safe).
extern "C" void kernel_launch(void* const* d_in, const int* in_sizes, int n_in,
                              void* d_out, int out_size, void* d_ws, size_t ws_size,
                              hipStream_t stream) {
    const float* h  = (const float*)d_in[0];   // [4,8192,1024]
    const float* Wq = (const float*)d_in[1];   // [1024,1024]
    const float* Wo = (const float*)d_in[7];   // [1024,1024]
    const float* M0 = (const float*)d_in[8];   // [4,16,64,64]
    float* out = (float*)d_out;

    char* ws = (char*)d_ws;
    u16*   hbf  = (u16*)d_out;                 // 67,108,864 B (first half of out)
    u16*   P    = (u16*)(ws);                  // 67,108,864 B
    u16*   WqT  = (u16*)(ws + 67108864);       //  2,097,152 B
    u16*   W2T  = (u16*)(ws + 69206016);       //  8,388,608 B
    float* ssq  = (float*)(ws + 77594624);     //    131,072 B  (end: 77,725,696)

    const int M = 32768, N = 1024, K = 1024;

    // one dispatch: cvt + WqT transpose + W2T build + ssq zero
    prep<<<16896, 256, 0, stream>>>(h, hbf, Wq, WqT, M0, Wo, W2T, ssq);
    // P = h @ Wq (bf16, un-normalized) + per-row ssq via atomics
    gemm256<1, 0, u16><<<512, 512, 0, stream>>>(
        hbf, WqT, P, ssq, M, N, K, 0, 0);
    // out = (1/max(sqrt(ssq),1e-12))[m] * (P @ W2T[batch]) ; batch = m >> 13
    gemm256<0, 1, float><<<512, 512, 0, stream>>>(
        P, W2T, out, ssq, M, N, K, 1024 * 1024, 13);
}

// Round 8
// 199.077 us; speedup vs baseline: 1.1054x; 1.0481x over previous
//
#include <hip/hip_runtime.h>

typedef unsigned short u16;
typedef __bf16 bf16x8 __attribute__((ext_vector_type(8)));
typedef float   f32x4 __attribute__((ext_vector_type(4)));
typedef unsigned short u16x8 __attribute__((ext_vector_type(8)));

// ---------- helpers ----------
__device__ __forceinline__ u16 f2bf(float f) {
    unsigned int u = __builtin_bit_cast(unsigned int, f);
    u = u + 0x7FFFu + ((u >> 16) & 1u);   // round-to-nearest-even
    return (u16)(u >> 16);
}
__device__ __forceinline__ void gload16(const void* g, void* l) {
    __builtin_amdgcn_global_load_lds(
        (__attribute__((address_space(1))) void*)g,
        (__attribute__((address_space(3))) void*)l,
        16, 0, 0);
}

// ---------- kernel 1: fp32 -> bf16 cast (h) ----------
// Standalone (R7 lesson: merging with the VGPR-112 build branch dropped
// occupancy to 16% and cvt BW to 1.8 TB/s; alone it runs ~16 VGPR @ ~6 TB/s).
__global__ __launch_bounds__(256) void cvt_bf16(const float* __restrict__ x,
                                                u16* __restrict__ y) {
    int i = blockIdx.x * 256 + threadIdx.x;
    const f32x4* xp = (const f32x4*)x + (size_t)i * 2;
    f32x4 a = xp[0], b = xp[1];
    u16x8 o;
    o[0]=f2bf(a[0]); o[1]=f2bf(a[1]); o[2]=f2bf(a[2]); o[3]=f2bf(a[3]);
    o[4]=f2bf(b[0]); o[5]=f2bf(b[1]); o[6]=f2bf(b[2]); o[7]=f2bf(b[3]);
    ((u16x8*)y)[i] = o;
}

// ---------- small prep: WqT transpose | W2T build + ssq zero ----------
// 512 blocks: [0,256) transpose, [256,512) build. Register-fat build branch
// is fine here — this kernel is ~5 us and not BW-critical.
__global__ __launch_bounds__(256) void small_prep(
    const float* __restrict__ Wq, u16* __restrict__ WqT,
    const float* __restrict__ M0, const float* __restrict__ Wo,
    u16* __restrict__ W2T, float* __restrict__ ssq) {
    __shared__ __align__(16) char smem[16384];
    const int bid = blockIdx.x;
    const int tid = threadIdx.x;
    if (bid < 256) {
        // Wq [K][N] fp32 -> WqT [N][K] bf16
        u16 (*tile)[65] = (u16(*)[65])smem;
        const int c0 = (bid & 15) * 64;
        const int r0 = (bid >> 4) * 64;
        const int col = tid & 63;
        const int rb  = (tid >> 6) * 16;
        #pragma unroll
        for (int rr = 0; rr < 16; ++rr)
            tile[rb + rr][col] = f2bf(Wq[(size_t)(r0 + rb + rr) * 1024 + c0 + col]);
        __syncthreads();
        const int k = tid & 63;
        #pragma unroll
        for (int rr = 0; rr < 16; ++rr) {
            int n = c0 + rb + rr;
            WqT[(size_t)n * 1024 + r0 + k] = tile[k][rb + rr];
        }
    } else {
        // W2T[b][j][h*64+d] = sum_e M0[b,h,d,e]*Wo[h*64+e][j]; also zero ssq
        const int local = bid - 256;             // 0..255
        const int jq = local & 3;
        const int hh = (local >> 2) & 15;
        const int bb = local >> 6;
        if (local < 128) ssq[local * 256 + tid] = 0.f;   // 128*256 = 32768
        const int j = jq * 256 + tid;
        float* m0s = (float*)smem;               // 4096 floats
        const float* m0p = M0 + ((size_t)bb * 16 + hh) * 4096;
        for (int i = tid; i < 4096; i += 256) m0s[i] = m0p[i];
        __syncthreads();
        float wo[64];
        #pragma unroll
        for (int e = 0; e < 64; ++e) wo[e] = Wo[(size_t)(hh * 64 + e) * 1024 + j];
        u16* outp = W2T + (size_t)bb * 1024 * 1024 + (size_t)j * 1024 + hh * 64;
        #pragma unroll 1
        for (int d = 0; d < 64; ++d) {
            float s = 0.f;
            #pragma unroll
            for (int e = 0; e < 64; ++e) s += m0s[d * 64 + e] * wo[e];
            outp[d] = f2bf(s);
        }
    }
}

// ---------- GEMM: C[M,N] = A[M,K] * Bt[N,K]^T, bf16 in, fp32 acc ----------
// R1-verified 256x256/BK=64 8-phase loop (T2 swizzle, T3+T4 counted vmcnt,
// T5 setprio). R8: JOB-CHAINED — grid 256 (1 block/CU), each block runs
// tile b then b+256. The last K-iteration's wrap-stages (previously wasted)
// are redirected to prefetch job1's tile0 A+B and tile1 B, so job1 enters
// its K-loop in the exact prologue-equivalent state:
//   peel-P4 vmcnt(4): drains A(buf1,15); leaves B_next(buf0) in flight
//   peel-P8 vmcnt(4): drains B_next(buf0)+A_next(buf0); leaves B_next(buf1)
// Epilogues are LDS-free (ssq via direct global atomics / scale via direct
// loads) => NO syncthreads/vmcnt(0) between jobs; job0's epilogue stores
// overlap job1's P1-P3 (they are drained harmlessly by job1's first
// vmcnt(4), which over-waits but stays correct).
// [Ledger: R2/R6 fp32-A staging, R3 LDS-coalesced epilogue, R4 fusion,
//  R5 epoch-shift all neutral-or-worse; this keeps the verified skeleton.]
template <int ACC_SSQ, int HAS_SCALE, typename CT>
__global__ __launch_bounds__(512, 2) void gemm256(const u16* __restrict__ A,
                                                  const u16* __restrict__ Bt,
                                                  CT* __restrict__ C,
                                                  float* __restrict__ ssq,
                                                  int N, int K,
                                                  int bt_batch_stride, int rpb_log2) {
    __shared__ __align__(16) u16 lds[65536];   // 131072 B
    const int tid  = threadIdx.x;
    const int lane = tid & 63;
    const int w    = tid >> 6;       // 0..7
    const int wm   = w >> 2;         // 0..1
    const int wn   = w & 3;          // 0..3

    char* const ldsb = (char*)lds;
    const int l3   = lane >> 3;
    const int co   = ((lane & 7) ^ l3) * 8;
    const int wdst = w * 2048;
    const int rm   = lane & 15;
    const int kq   = (lane >> 4) * 16;
    const int swzr = (rm & 7) << 4;
    const int cn   = lane & 15;
    const int rq   = (lane >> 4) * 4;

    // XCD swizzle (512 logical tiles = 128 mt x 4 nt; id and id+256 share xcd)
    int m0, n0, m0n, n0n;
    const u16 *gA, *gB, *gAn, *gBn;
    auto setjob = [&](int idv, const u16*& pa, const u16*& pb, int& pm, int& pn) {
        const int xcd = idv & 7;
        const int loc = idv >> 3;
        const int mt  = xcd * 16 + (loc >> 2);
        const int nt  = loc & 3;
        pm = mt * 256;
        pn = nt * 256;
        const u16* btb = Bt + (size_t)(pm >> rpb_log2) * (size_t)bt_batch_stride;
        pa = A   + (size_t)(pm + w * 16 + l3) * K + co;
        pb = btb + (size_t)(pn + w * 16 + l3) * K + co;
    };
    setjob((int)blockIdx.x, gA, gB, m0, n0);

    // ---- staging (gload_lds; per-lane global src carries inverse swizzle) ----
    auto stA_ = [&](const u16* base, int buf, int h, int kt) {
        const u16* s = base + (size_t)(h * 128) * K + kt * 64;
        char* d = ldsb + (buf * 2 + h) * 16384 + wdst;
        gload16(s, d);
        gload16(s + (size_t)8 * K, d + 1024);
    };
    auto stB_ = [&](const u16* base, int buf, int h, int kt) {
        const u16* s = base + (size_t)(h * 128) * K + kt * 64;
        char* d = ldsb + 65536 + (buf * 2 + h) * 16384 + wdst;
        gload16(s, d);
        gload16(s + (size_t)8 * K, d + 1024);
    };

    // ---- fragment reads (swizzled ds_read_b128) ----
    auto ldA = [&](int buf, int qm, int m, int ks) -> bf16x8 {
        const int row = qm * 64 + m * 16 + rm;
        return *(const bf16x8*)(ldsb + (buf * 2 + wm) * 16384 + row * 128
                                + ((ks * 64 + kq) ^ swzr));
    };
    auto ldB = [&](int buf, int qn, int n, int ks) -> bf16x8 {
        const int row = (wn & 1) * 64 + qn * 32 + n * 16 + rm;
        return *(const bf16x8*)(ldsb + 65536 + (buf * 2 + (wn >> 1)) * 16384
                                + row * 128 + ((ks * 64 + kq) ^ swzr));
    };

    f32x4 acc[8][4] = {};
    bf16x8 a[8];
    bf16x8 b[2][4];

#define LOADA(buf, qm)                                                         \
    { _Pragma("unroll") for (int m_ = 0; m_ < 4; ++m_) {                       \
        _Pragma("unroll") for (int k_ = 0; k_ < 2; ++k_)                       \
            a[m_ * 2 + k_] = ldA(buf, qm, m_, k_); } }
#define LOADB(buf, qn)                                                         \
    { _Pragma("unroll") for (int n_ = 0; n_ < 2; ++n_) {                       \
        _Pragma("unroll") for (int k_ = 0; k_ < 2; ++k_)                       \
            b[qn][n_ * 2 + k_] = ldB(buf, qn, n_, k_); } }
#define MFMAQ(qm, qn)                                                          \
    { __builtin_amdgcn_s_setprio(1);                                           \
      _Pragma("unroll") for (int m_ = 0; m_ < 4; ++m_) {                       \
        _Pragma("unroll") for (int n_ = 0; n_ < 2; ++n_) {                     \
          _Pragma("unroll") for (int k_ = 0; k_ < 2; ++k_)                     \
            acc[(qm) * 4 + m_][(qn) * 2 + n_] =                                \
                __builtin_amdgcn_mfma_f32_16x16x32_bf16(                       \
                    a[m_ * 2 + k_], b[qn][n_ * 2 + k_],                        \
                    acc[(qm) * 4 + m_][(qn) * 2 + n_], 0, 0, 0); } }           \
      __builtin_amdgcn_s_setprio(0); }
#define LGKM8 asm volatile("s_waitcnt lgkmcnt(8)" ::: "memory")
#define LGKM0 asm volatile("s_waitcnt lgkmcnt(0)" ::: "memory")
#define VMC4  asm volatile("s_waitcnt vmcnt(4)" ::: "memory")
#define BAR   __builtin_amdgcn_s_barrier()

    // ---- prologue: tile0 (4 halves) + tile1 (B halves) of job0 ----
    stA_(gA, 0, 0, 0); stA_(gA, 0, 1, 0); stB_(gB, 0, 0, 0); stB_(gB, 0, 1, 0);
    stB_(gB, 1, 0, 1); stB_(gB, 1, 1, 1);
    VMC4;
    BAR;

    #pragma unroll 1
    for (int j = 0; j < 2; ++j) {
        if (j == 0) setjob((int)blockIdx.x + 256, gAn, gBn, m0n, n0n);
        else { gAn = gA; gBn = gB; }

        // ---- 7 normal iterations ----
        #pragma unroll 1
        for (int i = 0; i < 7; ++i) {
            const int T1 = 2 * i + 1;
            const int T2 = 2 * i + 2;
            const int T3 = 2 * i + 3;
            // P1
            LOADA(0, 0); LOADB(0, 0);
            stA_(gA, 1, 0, T1);
            LGKM8; BAR; LGKM0;
            MFMAQ(0, 0); BAR;
            // P2
            LOADB(0, 1);
            stA_(gA, 1, 1, T1);
            BAR; LGKM0;
            MFMAQ(0, 1); BAR;
            // P3
            LOADA(0, 1);
            stB_(gB, 0, 0, T2);
            BAR; LGKM0;
            MFMAQ(1, 0); BAR;
            // P4
            stB_(gB, 0, 1, T2);
            VMC4; BAR;
            MFMAQ(1, 1); BAR;
            // P5
            LOADA(1, 0); LOADB(1, 0);
            stA_(gA, 0, 0, T2);
            LGKM8; BAR; LGKM0;
            MFMAQ(0, 0); BAR;
            // P6
            LOADB(1, 1);
            stA_(gA, 0, 1, T2);
            BAR; LGKM0;
            MFMAQ(0, 1); BAR;
            // P7
            LOADA(1, 1);
            stB_(gB, 1, 0, T3);
            BAR; LGKM0;
            MFMAQ(1, 0); BAR;
            // P8
            stB_(gB, 1, 1, T3);
            VMC4; BAR;
            MFMAQ(1, 1); BAR;
        }

        // ---- peeled last iteration: stages target NEXT job's tiles ----
        // P1
        LOADA(0, 0); LOADB(0, 0);
        stA_(gA, 1, 0, 15);
        LGKM8; BAR; LGKM0;
        MFMAQ(0, 0); BAR;
        // P2
        LOADB(0, 1);
        stA_(gA, 1, 1, 15);
        BAR; LGKM0;
        MFMAQ(0, 1); BAR;
        // P3
        LOADA(0, 1);
        stB_(gBn, 0, 0, 0);
        BAR; LGKM0;
        MFMAQ(1, 0); BAR;
        // P4  (drains A(buf1,15); leaves B_next(buf0) in flight)
        stB_(gBn, 0, 1, 0);
        VMC4; BAR;
        MFMAQ(1, 1); BAR;
        // P5
        LOADA(1, 0); LOADB(1, 0);
        stA_(gAn, 0, 0, 0);
        LGKM8; BAR; LGKM0;
        MFMAQ(0, 0); BAR;
        // P6
        LOADB(1, 1);
        stA_(gAn, 0, 1, 0);
        BAR; LGKM0;
        MFMAQ(0, 1); BAR;
        // P7
        LOADA(1, 1);
        stB_(gBn, 1, 0, 1);
        BAR; LGKM0;
        MFMAQ(1, 0); BAR;
        // P8  (drains B_next(buf0)+A_next(buf0); leaves B_next(buf1))
        stB_(gBn, 1, 1, 1);
        VMC4; BAR;
        MFMAQ(1, 1); BAR;

        // ---- LDS-free epilogue (no syncthreads, no vmcnt drain) ----
        // C layout: col=lane&15, row=(lane>>4)*4+reg [m89]
        #pragma unroll
        for (int m = 0; m < 8; ++m) {
            const int rbase = wm * 128 + m * 16 + rq;
            #pragma unroll
            for (int r = 0; r < 4; ++r) {
                const int row = m0 + rbase + r;
                const size_t rowoff = (size_t)row * N;
                if constexpr (ACC_SSQ) {
                    float s = 0.f;
                    #pragma unroll
                    for (int n = 0; n < 4; ++n) {
                        float x = acc[m][n][r];
                        s += x * x;
                        ((u16*)C)[rowoff + n0 + wn * 64 + n * 16 + cn] = f2bf(x);
                    }
                    s += __shfl_xor(s, 1);
                    s += __shfl_xor(s, 2);
                    s += __shfl_xor(s, 4);
                    s += __shfl_xor(s, 8);
                    if (cn == 0) atomicAdd(&ssq[row], s);   // 16 adds/row total
                } else {
                    float sc = 1.0f;
                    if constexpr (HAS_SCALE) {
                        float qv = ssq[row];                // L1/L2-hot (1KB/block)
                        sc = 1.0f / fmaxf(sqrtf(qv), 1e-12f);
                    }
                    #pragma unroll
                    for (int n = 0; n < 4; ++n)
                        C[rowoff + n0 + wn * 64 + n * 16 + cn] = acc[m][n][r] * sc;
                }
            }
        }

        // ---- advance to job1 ----
        if (j == 0) {
            gA = gAn; gB = gBn; m0 = m0n; n0 = n0n;
            #pragma unroll
            for (int mm = 0; mm < 8; ++mm)
                #pragma unroll
                for (int nn = 0; nn < 4; ++nn)
                    acc[mm][nn] = f32x4{0.f, 0.f, 0.f, 0.f};
        }
    }
#undef LOADA
#undef LOADB
#undef MFMAQ
#undef LGKM8
#undef LGKM0
#undef VMC4
#undef BAR
}

// ---------- launch ----------
// B=4, S=8192, HID=PROJ=1024, NH=16, HD=64; M = B*S = 32768
// hbf lives in d_out's first half (dead after gemm1; gemm2 overwrites all
// of d_out — stream-ordered, safe).
extern "C" void kernel_launch(void* const* d_in, const int* in_sizes, int n_in,
                              void* d_out, int out_size, void* d_ws, size_t ws_size,
                              hipStream_t stream) {
    const float* h  = (const float*)d_in[0];   // [4,8192,1024]
    const float* Wq = (const float*)d_in[1];   // [1024,1024]
    const float* Wo = (const float*)d_in[7];   // [1024,1024]
    const float* M0 = (const float*)d_in[8];   // [4,16,64,64]
    float* out = (float*)d_out;

    char* ws = (char*)d_ws;
    u16*   hbf  = (u16*)d_out;                 // 67,108,864 B (first half of out)
    u16*   P    = (u16*)(ws);                  // 67,108,864 B
    u16*   WqT  = (u16*)(ws + 67108864);       //  2,097,152 B
    u16*   W2T  = (u16*)(ws + 69206016);       //  8,388,608 B
    float* ssq  = (float*)(ws + 77594624);     //    131,072 B  (end: 77,725,696)

    const int N = 1024, K = 1024;

    cvt_bf16<<<16384, 256, 0, stream>>>(h, hbf);
    small_prep<<<512, 256, 0, stream>>>(Wq, WqT, M0, Wo, W2T, ssq);
    // P = h @ Wq (bf16, un-normalized) + per-row ssq via atomics
    gemm256<1, 0, u16><<<256, 512, 0, stream>>>(
        hbf, WqT, P, ssq, N, K, 0, 0);
    // out = (1/max(sqrt(ssq),1e-12))[m] * (P @ W2T[batch]) ; batch = m >> 13
    gemm256<0, 1, float><<<256, 512, 0, stream>>>(
        P, W2T, out, ssq, N, K, 1024 * 1024, 13);
}